// Round 5
// baseline (79.988 us; speedup 1.0000x reference)
//
#include <hip/hip_runtime.h>
#include <math.h>

#define N_LB  1024
#define N_ULB 7168
#define NTOT  8192
#define DD    128
#define CC    10

// float offsets into d_out
#define O_ANCHOR 0
#define O_POS    917504
#define O_LBF    1835008
#define O_LBOH   1966080
#define O_LLB    1976320
#define O_LULB1  1986560
#define O_LULB2  2058240
#define O_CN     2129920

typedef short bf16x8 __attribute__((ext_vector_type(8)));
typedef float f32x16 __attribute__((ext_vector_type(16)));

__device__ __forceinline__ ushort f2bf(float f) {
  union { float f; unsigned u; } a; a.f = f;
  unsigned r = a.u + 0x7FFFu + ((a.u >> 16) & 1u);   // RNE
  return (ushort)(r >> 16);
}
__device__ __forceinline__ float bf2f(ushort u) {
  union { unsigned u; float f; } a; a.u = ((unsigned)u) << 16; return a.f;
}

// Fragment-major Q layout: 16B chunk (8 bf16) for global row r, col-chunk kc
// (cols kc*8..kc*8+7) at ushort offset tile*4096 + (kc>>1)*512 + ((r&31)+32*(kc&1))*8.
// Every MFMA A/B fragment load is lane-contiguous (1KB/instruction).
__device__ __forceinline__ size_t qfrag_off(int r, int kc) {
  return (size_t)(r >> 5) * 4096 + (size_t)(kc >> 1) * 512
       + (size_t)((r & 31) + 32 * (kc & 1)) * 8;
}

// -------- prep: copies + frag-major bf16 staging + single-block class_num ---
__global__ __launch_bounds__(256) void prep_kernel(
    const float* __restrict__ anchor, const float* __restrict__ positive,
    const float* __restrict__ lb_feat, const float* __restrict__ lb_oh,
    const float* __restrict__ lulb1, const float* __restrict__ lulb2,
    const int* __restrict__ y_lb, float* __restrict__ out, ushort* __restrict__ Qf)
{
  const int blk = blockIdx.x;
  if (blk < 2000) {
    int t = blk * 256 + threadIdx.x;
    if (t < 229376) {                       // anchor: copy + bf16 frag-major
      float4 v = ((const float4*)anchor)[t];
      ((float4*)(out + O_ANCHOR))[t] = v;
      ushort4 u; u.x = f2bf(v.x); u.y = f2bf(v.y); u.z = f2bf(v.z); u.w = f2bf(v.w);
      int r = N_LB + (t >> 5), c4 = t & 31;
      *(ushort4*)(Qf + qfrag_off(r, c4 >> 1) + (c4 & 1) * 4) = u;
    } else if (t < 458752) {                // positive: copy
      int t2 = t - 229376;
      ((float4*)(out + O_POS))[t2] = ((const float4*)positive)[t2];
    } else if (t < 491520) {                // lb_feat: copy + bf16 frag-major
      int t2 = t - 458752;
      float4 v = ((const float4*)lb_feat)[t2];
      ((float4*)(out + O_LBF))[t2] = v;
      ushort4 u; u.x = f2bf(v.x); u.y = f2bf(v.y); u.z = f2bf(v.z); u.w = f2bf(v.w);
      int r = t2 >> 5, c4 = t2 & 31;
      *(ushort4*)(Qf + qfrag_off(r, c4 >> 1) + (c4 & 1) * 4) = u;
    } else if (t < 494080) {                // lb_one_hot: copy
      int t2 = t - 491520;
      ((float4*)(out + O_LBOH))[t2] = ((const float4*)lb_oh)[t2];
    } else {                                // lulb2: copy
      int t2 = t - 494080;
      ((float4*)(out + O_LULB2))[t2] = ((const float4*)lulb2)[t2];
    }
  } else {
    // single-block class_num: LDS histogram, direct store (no memset needed)
    __shared__ int cnt[CC];
    if (threadIdx.x < CC) cnt[threadIdx.x] = 0;
    __syncthreads();
    for (int it = 0; it < 32; ++it) {
      int t = threadIdx.x + it * 256;       // 0..8191
      if (t < N_ULB) {
        float a[CC], b[CC];
        #pragma unroll
        for (int c = 0; c < CC; ++c) { a[c] = lulb1[t * CC + c]; b[c] = lulb2[t * CC + c]; }
        float m1 = -INFINITY, m2 = -INFINITY;
        #pragma unroll
        for (int c = 0; c < CC; ++c) { m1 = fmaxf(m1, 2.f * a[c]); m2 = fmaxf(m2, 2.f * b[c]); }
        float Z1 = 0.f, Z2 = 0.f;
        #pragma unroll
        for (int c = 0; c < CC; ++c) { Z1 += expf(2.f * a[c] - m1); Z2 += expf(2.f * b[c] - m2); }
        bool gt = (1.0f / Z1) >= (1.0f / Z2);
        float g[CC];
        #pragma unroll
        for (int c = 0; c < CC; ++c) g[c] = gt ? a[c] : b[c];
        float mg = -INFINITY;
        #pragma unroll
        for (int c = 0; c < CC; ++c) mg = fmaxf(mg, g[c]);
        float p[CC]; float Zg = 0.f;
        #pragma unroll
        for (int c = 0; c < CC; ++c) { p[c] = expf(g[c] - mg); Zg += p[c]; }
        float best = ((p[0] / Zg) >= 0.95f) ? g[0] : 0.0f;
        int bi = 0;
        #pragma unroll
        for (int c = 1; c < CC; ++c) {
          float v = ((p[c] / Zg) >= 0.95f) ? g[c] : 0.0f;
          if (v > best) { best = v; bi = c; }
        }
        if (best != 0.0f) atomicAdd(&cnt[bi], 1);
      } else {
        atomicAdd(&cnt[y_lb[t - N_ULB]], 1);
      }
    }
    __syncthreads();
    if (threadIdx.x < CC) out[O_CN + threadIdx.x] = (float)cnt[threadIdx.x];
  }
}

// -------- attn_main: 256 blocks = 128 row-groups x 2 j-halves, 12 waves -----
// Block owns 64 A-rows (frags in regs per wave); waves stride the 128 j-tiles.
// Rare exp path reduces immediately into LDS (no persistent Z/vm registers).
__global__ __launch_bounds__(768, 3) void attn_main(
    const ushort* __restrict__ Qf, float* __restrict__ part)
{
  __shared__ float lz[12][64];
  __shared__ float lv[12][64];

  const int tid = threadIdx.x;
  const int w  = tid >> 6;          // 0..11
  const int l  = tid & 63;
  const int lr = l & 31;
  const int kh = l >> 5;
  const int g  = blockIdx.x >> 1;   // rows g*64 .. g*64+63
  const int h  = blockIdx.x & 1;    // j-half

  // zero LDS merge buffers
  lz[w][l] = 0.0f; lv[w][l] = 0.0f;

  bf16x8 a0[8], a1[8];
  {
    const ushort* p0 = Qf + (size_t)(2 * g)     * 4096 + l * 8;
    const ushort* p1 = Qf + (size_t)(2 * g + 1) * 4096 + l * 8;
    #pragma unroll
    for (int e = 0; e < 8; ++e) {
      a0[e] = *(const bf16x8*)(p0 + e * 512);
      a1[e] = *(const bf16x8*)(p1 + e * 512);
    }
  }

  // per-row references ||q||^2
  float n0 = 0.f, n1 = 0.f;
  #pragma unroll
  for (int e = 0; e < 8; ++e) {
    #pragma unroll
    for (int k = 0; k < 8; ++k) {
      float q0 = bf2f((ushort)a0[e][k]); n0 = fmaf(q0, q0, n0);
      float q1 = bf2f((ushort)a1[e][k]); n1 = fmaf(q1, q1, n1);
    }
  }
  n0 += __shfl_xor(n0, 32);
  n1 += __shfl_xor(n1, 32);

  // conservative skip threshold: min reference over the block's 64 rows
  float nm = fminf(n0, n1);
  #pragma unroll
  for (int off = 1; off <= 16; off <<= 1) nm = fminf(nm, __shfl_xor(nm, off));
  const float thr = nm - 2.0f;

  __syncthreads();   // LDS zeros visible

  for (int t = w; t < 128; t += 12) {
    const int j0 = (h * 128 + t) * 32;
    const ushort* bp = Qf + (size_t)(h * 128 + t) * 4096 + l * 8;
    bf16x8 b[8];
    #pragma unroll
    for (int e = 0; e < 8; ++e) b[e] = *(const bf16x8*)(bp + e * 512);

    f32x16 c0, c1;
    #pragma unroll
    for (int e = 0; e < 16; ++e) { c0[e] = 0.0f; c1[e] = 0.0f; }
    #pragma unroll
    for (int e = 0; e < 8; ++e) {
      c0 = __builtin_amdgcn_mfma_f32_32x32x16_bf16(a0[e], b[e], c0, 0, 0, 0);
      c1 = __builtin_amdgcn_mfma_f32_32x32x16_bf16(a1[e], b[e], c1, 0, 0, 0);
    }

    float dm = -INFINITY;
    #pragma unroll
    for (int e = 0; e < 16; ++e) dm = fmaxf(dm, fmaxf(c0[e], c1[e]));

    if (__any(dm > thr)) {                      // rare: ~2 tiles per block
      const int jj = j0 + lr;
      #pragma unroll
      for (int e = 0; e < 16; ++e) {
        int rr = (e & 3) + 8 * (e >> 2) + 4 * kh;
        float r0 = __shfl(n0, rr), r1 = __shfl(n1, rr);
        float e0 = __expf((c0[e] - r0) * 10.f);
        float e1 = __expf((c1[e] - r1) * 10.f);
        float v0 = __int_as_float((__float_as_int(e0) & 0xFFFFE000) | jj);
        float v1 = __int_as_float((__float_as_int(e1) & 0xFFFFE000) | jj);
        float Zr0 = e0, Zr1 = e1;
        #pragma unroll
        for (int off = 1; off <= 16; off <<= 1) {
          Zr0 += __shfl_xor(Zr0, off);
          Zr1 += __shfl_xor(Zr1, off);
          v0 = fmaxf(v0, __shfl_xor(v0, off));
          v1 = fmaxf(v1, __shfl_xor(v1, off));
        }
        if (lr == 0) {
          lz[w][rr]      += Zr0;  lv[w][rr]      = fmaxf(lv[w][rr],      v0);
          lz[w][32 + rr] += Zr1;  lv[w][32 + rr] = fmaxf(lv[w][32 + rr], v1);
        }
      }
    }
  }

  __syncthreads();

  if (tid < 64) {
    float Zf = 0.f, vf = 0.f;
    #pragma unroll
    for (int wv = 0; wv < 12; ++wv) { Zf += lz[wv][tid]; vf = fmaxf(vf, lv[wv][tid]); }
    part[(size_t)(blockIdx.x * 64 + tid) * 2]     = Zf;
    part[(size_t)(blockIdx.x * 64 + tid) * 2 + 1] = vf;
  }
}

// -------- attn_final: merge j-half partials + epilogue ----------------------
__global__ __launch_bounds__(256) void attn_final(
    const float* __restrict__ part, const float* __restrict__ lb_one_hot,
    const float* __restrict__ lulb1, float* __restrict__ out)
{
  int i = blockIdx.x * 256 + threadIdx.x;   // global row 0..8191
  if (i >= NTOT) return;
  int g = i >> 6, loc = i & 63;
  size_t i0 = (size_t)((g * 2)     * 64 + loc) * 2;
  size_t i1 = (size_t)((g * 2 + 1) * 64 + loc) * 2;
  float Zf = part[i0] + part[i1];
  float vf = fmaxf(part[i0 + 1], part[i1 + 1]);
  unsigned bits = __float_as_uint(vf);
  float exm = __uint_as_float(bits & 0xFFFFE000u);
  int   jf  = (int)(bits & 8191u);
  float av = exm / Zf;
  float* orow = (i < N_LB) ? (out + O_LLB + (size_t)i * CC)
                           : (out + O_LULB1 + (size_t)(i - N_LB) * CC);
  if (av >= 0.6f) {
    if (jf < N_LB) {
      #pragma unroll
      for (int c = 0; c < CC; ++c) orow[c] = av * lb_one_hot[jf * CC + c];
    } else {
      const float* lg = lulb1 + (size_t)(jf - N_LB) * CC;
      float mx = lg[0];
      #pragma unroll
      for (int c = 1; c < CC; ++c) mx = fmaxf(mx, lg[c]);
      float e[CC]; float sum = 0.f;
      #pragma unroll
      for (int c = 0; c < CC; ++c) { e[c] = expf(lg[c] - mx); sum += e[c]; }
      #pragma unroll
      for (int c = 0; c < CC; ++c) orow[c] = av * (e[c] / sum);
    }
  } else {
    #pragma unroll
    for (int c = 0; c < CC; ++c) orow[c] = 0.0f;
  }
}

extern "C" void kernel_launch(void* const* d_in, const int* in_sizes, int n_in,
                              void* d_out, int out_size, void* d_ws, size_t ws_size,
                              hipStream_t stream) {
  (void)in_sizes; (void)n_in; (void)ws_size; (void)out_size;
  const float* anchor   = (const float*)d_in[0];
  const float* positive = (const float*)d_in[1];
  const float* lb_feat  = (const float*)d_in[2];
  const float* lb_oh    = (const float*)d_in[3];
  const float* lulb1    = (const float*)d_in[5];
  const float* lulb2    = (const float*)d_in[6];
  const int*   y_lb     = (const int*)d_in[7];
  float* out = (float*)d_out;
  ushort* Qf  = (ushort*)d_ws;                          // 2 MB fragment-major Q
  float* part = (float*)((char*)d_ws + (2u << 20));     // 128 KB partials

  prep_kernel<<<2001, 256, 0, stream>>>(anchor, positive, lb_feat, lb_oh,
                                        lulb1, lulb2, y_lb, out, Qf);
  attn_main<<<256, 768, 0, stream>>>(Qf, part);
  attn_final<<<32, 256, 0, stream>>>(part, lb_oh, lulb1, out);
}

// Round 6
// 40.775 us; speedup vs baseline: 1.9617x; 1.9617x over previous
//
#include <hip/hip_runtime.h>
#include <math.h>

#define N_LB  1024
#define N_ULB 7168
#define NTOT  8192
#define DD    128
#define CC    10

// float offsets into d_out
#define O_ANCHOR 0
#define O_POS    917504
#define O_LBF    1835008
#define O_LBOH   1966080
#define O_LLB    1976320
#define O_LULB1  1986560
#define O_LULB2  2058240
#define O_CN     2129920

typedef short bf16x8 __attribute__((ext_vector_type(8)));
typedef float f32x16 __attribute__((ext_vector_type(16)));

__device__ __forceinline__ ushort f2bf(float f) {
  union { float f; unsigned u; } a; a.f = f;
  unsigned r = a.u + 0x7FFFu + ((a.u >> 16) & 1u);   // RNE
  return (ushort)(r >> 16);
}
__device__ __forceinline__ float bf2f(ushort u) {
  union { unsigned u; float f; } a; a.u = ((unsigned)u) << 16; return a.f;
}

// Fragment-major Q layout: 16B chunk (8 bf16) for global row r, col-chunk kc
// (cols kc*8..kc*8+7) at ushort offset tile*4096 + (kc>>1)*512 + ((r&31)+32*(kc&1))*8.
// Every MFMA A/B fragment load is lane-contiguous (1KB/instruction).
__device__ __forceinline__ size_t qfrag_off(int r, int kc) {
  return (size_t)(r >> 5) * 4096 + (size_t)(kc >> 1) * 512
       + (size_t)((r & 31) + 32 * (kc & 1)) * 8;
}

// -------- prep: pure copies + frag-major bf16 staging -----------------------
__global__ __launch_bounds__(256) void prep_kernel(
    const float* __restrict__ anchor, const float* __restrict__ positive,
    const float* __restrict__ lb_feat, const float* __restrict__ lb_oh,
    const float* __restrict__ lulb2, float* __restrict__ out,
    ushort* __restrict__ Qf)
{
  int t = blockIdx.x * 256 + threadIdx.x;
  if (t < 229376) {                       // anchor: copy + bf16 frag-major
    float4 v = ((const float4*)anchor)[t];
    ((float4*)(out + O_ANCHOR))[t] = v;
    ushort4 u; u.x = f2bf(v.x); u.y = f2bf(v.y); u.z = f2bf(v.z); u.w = f2bf(v.w);
    int r = N_LB + (t >> 5), c4 = t & 31;
    *(ushort4*)(Qf + qfrag_off(r, c4 >> 1) + (c4 & 1) * 4) = u;
  } else if (t < 458752) {                // positive: copy
    int t2 = t - 229376;
    ((float4*)(out + O_POS))[t2] = ((const float4*)positive)[t2];
  } else if (t < 491520) {                // lb_feat: copy + bf16 frag-major
    int t2 = t - 458752;
    float4 v = ((const float4*)lb_feat)[t2];
    ((float4*)(out + O_LBF))[t2] = v;
    ushort4 u; u.x = f2bf(v.x); u.y = f2bf(v.y); u.z = f2bf(v.z); u.w = f2bf(v.w);
    int r = t2 >> 5, c4 = t2 & 31;
    *(ushort4*)(Qf + qfrag_off(r, c4 >> 1) + (c4 & 1) * 4) = u;
  } else if (t < 494080) {                // lb_one_hot: copy
    int t2 = t - 491520;
    ((float4*)(out + O_LBOH))[t2] = ((const float4*)lb_oh)[t2];
  } else {                                // lulb2: copy
    int t2 = t - 494080;
    ((float4*)(out + O_LULB2))[t2] = ((const float4*)lulb2)[t2];
  }
}

// -------- classnum: 32 blocks, per-block LDS hist -> partial counts in ws ---
__global__ __launch_bounds__(256) void classnum_kernel(
    const float* __restrict__ lulb1, const float* __restrict__ lulb2,
    const int* __restrict__ y_lb, float* __restrict__ cls_part)
{
  __shared__ int cnt[CC];
  if (threadIdx.x < CC) cnt[threadIdx.x] = 0;
  __syncthreads();
  int t = blockIdx.x * 256 + threadIdx.x;   // 0..8191
  if (t < N_ULB) {
    float a[CC], b[CC];
    #pragma unroll
    for (int c = 0; c < CC; ++c) { a[c] = lulb1[t * CC + c]; b[c] = lulb2[t * CC + c]; }
    float m1 = -INFINITY, m2 = -INFINITY;
    #pragma unroll
    for (int c = 0; c < CC; ++c) { m1 = fmaxf(m1, 2.f * a[c]); m2 = fmaxf(m2, 2.f * b[c]); }
    float Z1 = 0.f, Z2 = 0.f;
    #pragma unroll
    for (int c = 0; c < CC; ++c) { Z1 += expf(2.f * a[c] - m1); Z2 += expf(2.f * b[c] - m2); }
    bool gt = (1.0f / Z1) >= (1.0f / Z2);
    float g[CC];
    #pragma unroll
    for (int c = 0; c < CC; ++c) g[c] = gt ? a[c] : b[c];
    float mg = -INFINITY;
    #pragma unroll
    for (int c = 0; c < CC; ++c) mg = fmaxf(mg, g[c]);
    float p[CC]; float Zg = 0.f;
    #pragma unroll
    for (int c = 0; c < CC; ++c) { p[c] = expf(g[c] - mg); Zg += p[c]; }
    float best = ((p[0] / Zg) >= 0.95f) ? g[0] : 0.0f;
    int bi = 0;
    #pragma unroll
    for (int c = 1; c < CC; ++c) {
      float v = ((p[c] / Zg) >= 0.95f) ? g[c] : 0.0f;
      if (v > best) { best = v; bi = c; }
    }
    if (best != 0.0f) atomicAdd(&cnt[bi], 1);
  } else {
    atomicAdd(&cnt[y_lb[t - N_ULB]], 1);
  }
  __syncthreads();
  if (threadIdx.x < CC) cls_part[blockIdx.x * CC + threadIdx.x] = (float)cnt[threadIdx.x];
}

// -------- attn_main: 256 blocks = 128 row-groups x 2 j-halves, 12 waves -----
__global__ __launch_bounds__(768, 3) void attn_main(
    const ushort* __restrict__ Qf, float* __restrict__ part)
{
  __shared__ float lz[12][64];
  __shared__ float lv[12][64];

  const int tid = threadIdx.x;
  const int w  = tid >> 6;          // 0..11
  const int l  = tid & 63;
  const int lr = l & 31;
  const int kh = l >> 5;
  const int g  = blockIdx.x >> 1;   // rows g*64 .. g*64+63
  const int h  = blockIdx.x & 1;    // j-half

  lz[w][l] = 0.0f; lv[w][l] = 0.0f;

  bf16x8 a0[8], a1[8];
  {
    const ushort* p0 = Qf + (size_t)(2 * g)     * 4096 + l * 8;
    const ushort* p1 = Qf + (size_t)(2 * g + 1) * 4096 + l * 8;
    #pragma unroll
    for (int e = 0; e < 8; ++e) {
      a0[e] = *(const bf16x8*)(p0 + e * 512);
      a1[e] = *(const bf16x8*)(p1 + e * 512);
    }
  }

  // per-row references ||q||^2
  float n0 = 0.f, n1 = 0.f;
  #pragma unroll
  for (int e = 0; e < 8; ++e) {
    #pragma unroll
    for (int k = 0; k < 8; ++k) {
      float q0 = bf2f((ushort)a0[e][k]); n0 = fmaf(q0, q0, n0);
      float q1 = bf2f((ushort)a1[e][k]); n1 = fmaf(q1, q1, n1);
    }
  }
  n0 += __shfl_xor(n0, 32);
  n1 += __shfl_xor(n1, 32);

  // conservative skip threshold: min reference over the block's 64 rows
  float nm = fminf(n0, n1);
  #pragma unroll
  for (int off = 1; off <= 16; off <<= 1) nm = fminf(nm, __shfl_xor(nm, off));
  const float thr = nm - 2.0f;

  __syncthreads();   // LDS zeros visible

  for (int t = w; t < 128; t += 12) {
    const int j0 = (h * 128 + t) * 32;
    const ushort* bp = Qf + (size_t)(h * 128 + t) * 4096 + l * 8;
    bf16x8 b[8];
    #pragma unroll
    for (int e = 0; e < 8; ++e) b[e] = *(const bf16x8*)(bp + e * 512);

    f32x16 c0, c1;
    #pragma unroll
    for (int e = 0; e < 16; ++e) { c0[e] = 0.0f; c1[e] = 0.0f; }
    #pragma unroll
    for (int e = 0; e < 8; ++e) {
      c0 = __builtin_amdgcn_mfma_f32_32x32x16_bf16(a0[e], b[e], c0, 0, 0, 0);
      c1 = __builtin_amdgcn_mfma_f32_32x32x16_bf16(a1[e], b[e], c1, 0, 0, 0);
    }

    float dm = -INFINITY;
    #pragma unroll
    for (int e = 0; e < 16; ++e) dm = fmaxf(dm, fmaxf(c0[e], c1[e]));

    if (__any(dm > thr)) {                      // rare: ~2 tiles per block
      const int jj = j0 + lr;
      #pragma unroll
      for (int e = 0; e < 16; ++e) {
        int rr = (e & 3) + 8 * (e >> 2) + 4 * kh;
        float r0 = __shfl(n0, rr), r1 = __shfl(n1, rr);
        float e0 = __expf((c0[e] - r0) * 10.f);
        float e1 = __expf((c1[e] - r1) * 10.f);
        float v0 = __int_as_float((__float_as_int(e0) & 0xFFFFE000) | jj);
        float v1 = __int_as_float((__float_as_int(e1) & 0xFFFFE000) | jj);
        float Zr0 = e0, Zr1 = e1;
        #pragma unroll
        for (int off = 1; off <= 16; off <<= 1) {
          Zr0 += __shfl_xor(Zr0, off);
          Zr1 += __shfl_xor(Zr1, off);
          v0 = fmaxf(v0, __shfl_xor(v0, off));
          v1 = fmaxf(v1, __shfl_xor(v1, off));
        }
        if (lr == 0) {
          lz[w][rr]      += Zr0;  lv[w][rr]      = fmaxf(lv[w][rr],      v0);
          lz[w][32 + rr] += Zr1;  lv[w][32 + rr] = fmaxf(lv[w][32 + rr], v1);
        }
      }
    }
  }

  __syncthreads();

  if (tid < 64) {
    float Zf = 0.f, vf = 0.f;
    #pragma unroll
    for (int wv = 0; wv < 12; ++wv) { Zf += lz[wv][tid]; vf = fmaxf(vf, lv[wv][tid]); }
    part[(size_t)(blockIdx.x * 64 + tid) * 2]     = Zf;
    part[(size_t)(blockIdx.x * 64 + tid) * 2 + 1] = vf;
  }
}

// -------- attn_final: merge j-half partials + epilogue + class_num merge ----
__global__ __launch_bounds__(256) void attn_final(
    const float* __restrict__ part, const float* __restrict__ cls_part,
    const float* __restrict__ lb_one_hot, const float* __restrict__ lulb1,
    float* __restrict__ out)
{
  if (blockIdx.x == 0 && threadIdx.x < CC) {
    float s = 0.f;
    #pragma unroll
    for (int b = 0; b < 32; ++b) s += cls_part[b * CC + threadIdx.x];
    out[O_CN + threadIdx.x] = s;
  }
  int i = blockIdx.x * 256 + threadIdx.x;   // global row 0..8191
  if (i >= NTOT) return;
  int g = i >> 6, loc = i & 63;
  size_t i0 = (size_t)((g * 2)     * 64 + loc) * 2;
  size_t i1 = (size_t)((g * 2 + 1) * 64 + loc) * 2;
  float Zf = part[i0] + part[i1];
  float vf = fmaxf(part[i0 + 1], part[i1 + 1]);
  unsigned bits = __float_as_uint(vf);
  float exm = __uint_as_float(bits & 0xFFFFE000u);
  int   jf  = (int)(bits & 8191u);
  float av = exm / Zf;
  float* orow = (i < N_LB) ? (out + O_LLB + (size_t)i * CC)
                           : (out + O_LULB1 + (size_t)(i - N_LB) * CC);
  if (av >= 0.6f) {
    if (jf < N_LB) {
      #pragma unroll
      for (int c = 0; c < CC; ++c) orow[c] = av * lb_one_hot[jf * CC + c];
    } else {
      const float* lg = lulb1 + (size_t)(jf - N_LB) * CC;
      float mx = lg[0];
      #pragma unroll
      for (int c = 1; c < CC; ++c) mx = fmaxf(mx, lg[c]);
      float e[CC]; float sum = 0.f;
      #pragma unroll
      for (int c = 0; c < CC; ++c) { e[c] = expf(lg[c] - mx); sum += e[c]; }
      #pragma unroll
      for (int c = 0; c < CC; ++c) orow[c] = av * (e[c] / sum);
    }
  } else {
    #pragma unroll
    for (int c = 0; c < CC; ++c) orow[c] = 0.0f;
  }
}

extern "C" void kernel_launch(void* const* d_in, const int* in_sizes, int n_in,
                              void* d_out, int out_size, void* d_ws, size_t ws_size,
                              hipStream_t stream) {
  (void)in_sizes; (void)n_in; (void)ws_size; (void)out_size;
  const float* anchor   = (const float*)d_in[0];
  const float* positive = (const float*)d_in[1];
  const float* lb_feat  = (const float*)d_in[2];
  const float* lb_oh    = (const float*)d_in[3];
  const float* lulb1    = (const float*)d_in[5];
  const float* lulb2    = (const float*)d_in[6];
  const int*   y_lb     = (const int*)d_in[7];
  float* out = (float*)d_out;
  ushort* Qf   = (ushort*)d_ws;                              // 2 MB frag-major Q
  float* part  = (float*)((char*)d_ws + (2u << 20));         // 128 KB partials
  float* clsp  = (float*)((char*)d_ws + (2u << 20) + (128u << 10)); // 1.25 KB

  prep_kernel<<<2000, 256, 0, stream>>>(anchor, positive, lb_feat, lb_oh,
                                        lulb2, out, Qf);
  classnum_kernel<<<32, 256, 0, stream>>>(lulb1, lulb2, y_lb, clsp);
  attn_main<<<256, 768, 0, stream>>>(Qf, part);
  attn_final<<<32, 256, 0, stream>>>(part, clsp, lb_oh, lulb1, out);
}